// Round 15
// baseline (232.958 us; speedup 1.0000x reference)
//
#include <hip/hip_runtime.h>
#include <hip/hip_bf16.h>

using ushort_t = unsigned short;
using f32x4  = __attribute__((ext_vector_type(4))) float;
using short8 = __attribute__((ext_vector_type(8))) short;

// ---------- bf16 helpers ----------
__device__ __forceinline__ float bflo(unsigned p) {
    union { unsigned u; float f; } x; x.u = p << 16; return x.f;
}
__device__ __forceinline__ float bfhi(unsigned p) {
    union { unsigned u; float f; } x; x.u = p & 0xffff0000u; return x.f;
}
__device__ __forceinline__ ushort_t f2bf(float f) {
    __hip_bfloat16 h = __float2bfloat16(f);   // RTNE
    return *(ushort_t*)&h;
}
__device__ __forceinline__ unsigned pk2bf(float lo, float hi) {
    __hip_bfloat162 h = __float22bfloat162_rn({lo, hi});  // RTNE, packed
    return *(unsigned*)&h;
}

// ---------- combined weight prep ----------
__device__ __forceinline__ void tr_tile(const float* __restrict__ S, ushort_t* __restrict__ D,
                                        int K, int N, int Npad, int bx, int by,
                                        int tx, int ty, float* tile /*32*33*/)
{
    const int k0 = by * 32, n0 = bx * 32;
#pragma unroll
    for (int r = 0; r < 4; r++) {
        const int k = k0 + ty + r * 8, n = n0 + tx;
        tile[(ty + r * 8) * 33 + tx] = (k < K && n < N) ? S[(size_t)k * N + n] : 0.f;
    }
    __syncthreads();
#pragma unroll
    for (int r = 0; r < 4; r++) {
        const int n = n0 + ty + r * 8, k = k0 + tx;
        if (n < Npad && k < K) D[(size_t)n * K + k] = f2bf(tile[tx * 33 + ty + r * 8]);
    }
}

// fp32 -> fp32 transpose (for clf_W)
__device__ __forceinline__ void trf_tile(const float* __restrict__ S, float* __restrict__ D,
                                         int K, int N, int bx, int by,
                                         int tx, int ty, float* tile /*32*33*/)
{
    const int k0 = by * 32, n0 = bx * 32;
#pragma unroll
    for (int r = 0; r < 4; r++) {
        const int k = k0 + ty + r * 8, n = n0 + tx;
        tile[(ty + r * 8) * 33 + tx] = (k < K && n < N) ? S[(size_t)k * N + n] : 0.f;
    }
    __syncthreads();
#pragma unroll
    for (int r = 0; r < 4; r++) {
        const int n = n0 + ty + r * 8, k = k0 + tx;
        if (n < N && k < K) D[(size_t)n * K + k] = tile[tx * 33 + ty + r * 8];
    }
}

__global__ __launch_bounds__(256)
void prep_weights(const float* __restrict__ Wobj, ushort_t* __restrict__ WobjT,
                  const float* __restrict__ Wact, ushort_t* __restrict__ WactT,
                  const float* __restrict__ fc1W, ushort_t* __restrict__ fc1T,
                  const float* __restrict__ gc1W, ushort_t* __restrict__ W1t,
                  const float* __restrict__ gc3W, ushort_t* __restrict__ W3t,
                  const float* __restrict__ gc2W, ushort_t* __restrict__ W2bf,
                  const float* __restrict__ gc4W, ushort_t* __restrict__ W4bf,
                  const float* __restrict__ clfW, float* __restrict__ WclfT)
{
    __shared__ float tile[32 * 33];
    const int b = blockIdx.x;
    const int t = threadIdx.x;
    const int tx = t & 31, ty = t >> 5;

    if (b < 1056) {
        const float* S; ushort_t* D; int K, N, Npad, nt, l;
        if      (b < 256)  { S = Wobj; D = WobjT; K = 512; N = 512;  Npad = 512;  nt = 16; l = b; }
        else if (b < 512)  { S = Wact; D = WactT; K = 512; N = 512;  Npad = 512;  nt = 16; l = b - 256; }
        else if (b < 1024) { S = fc1W; D = fc1T;  K = 512; N = 1024; Npad = 1024; nt = 32; l = b - 512; }
        else if (b < 1040) { S = gc1W; D = W1t;   K = 512; N = 32;   Npad = 32;   nt = 1;  l = b - 1024; }
        else               { S = gc3W; D = W3t;   K = 512; N = 32;   Npad = 32;   nt = 1;  l = b - 1040; }
        tr_tile(S, D, K, N, Npad, l % nt, l / nt, tx, ty, tile);
    } else if (b < 1072) {
        const float* S = (b < 1064) ? gc2W : gc4W;
        ushort_t* D    = (b < 1064) ? W2bf : W4bf;
        const int i = (b < 1064 ? b - 1056 : b - 1064) * 256 + t;
        const float4 x = ((const float4*)S)[2 * i];
        const float4 y = ((const float4*)S)[2 * i + 1];
        unsigned r[4] = { pk2bf(x.x, x.y), pk2bf(x.z, x.w), pk2bf(y.x, y.y), pk2bf(y.z, y.w) };
        ((uint4*)D)[i] = *(uint4*)r;
    } else {
        const int l = b - 1072;
        trf_tile(clfW, WclfT, 1024, 500, l & 15, l >> 4, tx, ty, tile);
    }
}

// ---------- async DMA helper ----------
typedef __attribute__((address_space(1))) void glb_void;
typedef __attribute__((address_space(3))) void lds_void;
__device__ __forceinline__ void dma16(const void* g, void* l) {
    __builtin_amdgcn_global_load_lds((glb_void*)(unsigned long long)(uintptr_t)g,
                                     (lds_void*)(unsigned)(uintptr_t)l, 16, 0, 0);
}

// ---------- generic MFMA GEMM (proven; used for act) ----------
template<int RELU, typename AT>
__global__ __launch_bounds__(256)
void gemm_dma(const AT* __restrict__ A, const ushort_t* __restrict__ Bt,
              const float* __restrict__ bias, ushort_t* __restrict__ C,
              int N, int K, int Nb, int row_mul, int row_add)
{
    __shared__ __align__(16) char     AsRaw[128 * 32 * sizeof(AT)];
    __shared__ __align__(16) ushort_t Bs[128 * 32];
    const int t = threadIdx.x;
    const int lane = t & 63, w = t >> 6;
    const int bm = blockIdx.y * 128, bn = blockIdx.x * 128;
    const int mb = (w & 1) * 64, nb = (w >> 1) * 64;
    const int fr = lane & 15, fq = lane >> 4;

    f32x4 acc[16];
#pragma unroll
    for (int i = 0; i < 16; i++) acc[i] = (f32x4){0.f, 0.f, 0.f, 0.f};

    const int brow = lane >> 2, bk = lane & 3;
    const int klog = bk ^ ((brow >> 1) & 3);
    const int arow = lane >> 3, ag = lane & 7;

    for (int k0 = 0; k0 < K; k0 += 32) {
        __syncthreads();
        if constexpr (sizeof(AT) == 4) {
#pragma unroll
            for (int i = 0; i < 4; i++) {
                const int grp = w * 4 + i;
                const int row = grp * 8 + arow;
                const int gl = ag ^ (row & 7);
                dma16((const float*)A + (size_t)(bm + row) * K + k0 + gl * 4,
                      AsRaw + grp * 1024);
            }
        } else {
#pragma unroll
            for (int i = 0; i < 2; i++) {
                const int grp = w * 2 + i;
                const int row = grp * 16 + brow;
                dma16((const ushort_t*)A + (size_t)(bm + row) * K + k0 + klog * 8,
                      (ushort_t*)AsRaw + grp * 512);
            }
        }
#pragma unroll
        for (int i = 0; i < 2; i++) {
            const int grp = w * 2 + i;
            const int row = grp * 16 + brow;
            dma16(Bt + (size_t)(bn + row) * K + k0 + klog * 8, Bs + grp * 512);
        }
        __syncthreads();

        short8 af[4], bf[4];
        if constexpr (sizeof(AT) == 4) {
#pragma unroll
            for (int i = 0; i < 4; i++) {
                const int row = mb + i * 16 + fr;
                const float* base = (const float*)AsRaw + row * 32;
                const f32x4 p0 = *(const f32x4*)(base + (((2 * fq)     ^ (fr & 7)) * 4));
                const f32x4 p1 = *(const f32x4*)(base + (((2 * fq + 1) ^ (fr & 7)) * 4));
                unsigned rr[4] = { pk2bf(p0.x, p0.y), pk2bf(p0.z, p0.w),
                                   pk2bf(p1.x, p1.y), pk2bf(p1.z, p1.w) };
                af[i] = *(short8*)rr;
            }
        } else {
#pragma unroll
            for (int i = 0; i < 4; i++) {
                const int row = mb + i * 16 + fr;
                af[i] = *(const short8*)((const ushort_t*)AsRaw + row * 32 + (fq ^ ((fr >> 1) & 3)) * 8);
            }
        }
#pragma unroll
        for (int j = 0; j < 4; j++) {
            const int row = nb + j * 16 + fr;
            bf[j] = *(const short8*)(Bs + row * 32 + (fq ^ ((fr >> 1) & 3)) * 8);
        }
#pragma unroll
        for (int i = 0; i < 4; i++)
#pragma unroll
            for (int j = 0; j < 4; j++)
                acc[i * 4 + j] = __builtin_amdgcn_mfma_f32_16x16x32_bf16(
                    af[i], bf[j], acc[i * 4 + j], 0, 0, 0);
    }

#pragma unroll
    for (int j = 0; j < 4; j++) {
        const int n = bn + nb + j * 16 + fr;
        const float bv = (n < Nb) ? bias[n] : 0.f;
#pragma unroll
        for (int i = 0; i < 4; i++) {
            const f32x4 a = acc[i * 4 + j];
#pragma unroll
            for (int r = 0; r < 4; r++) {
                const int m = bm + mb + i * 16 + fq * 4 + r;
                float v = a[r] + bv;
                if (RELU) v = fmaxf(v, 0.f);
                C[((size_t)m * row_mul + row_add) * (size_t)N + n] = f2bf(v);
            }
        }
    }
}

// ---------- fc1 GEMM with fused T-mean epilogue (r3-proven) ----------
__global__ __launch_bounds__(256)
void gemm_fc1_mean(const ushort_t* __restrict__ A, const ushort_t* __restrict__ Bt,
                   const float* __restrict__ bias, float* __restrict__ cmean)
{
    __shared__ __align__(16) ushort_t AsS[128 * 32];
    __shared__ __align__(16) ushort_t Bs[128 * 32];
    const int t = threadIdx.x;
    const int lane = t & 63, w = t >> 6;
    const int bm = blockIdx.y * 128, bn = blockIdx.x * 128;
    const int mb = (w & 1) * 64, nb = (w >> 1) * 64;
    const int fr = lane & 15, fq = lane >> 4;
    const int K = 512;

    f32x4 acc[16];
#pragma unroll
    for (int i = 0; i < 16; i++) acc[i] = (f32x4){0.f, 0.f, 0.f, 0.f};

    const int brow = lane >> 2, bk = lane & 3;
    const int klog = bk ^ ((brow >> 1) & 3);

    for (int k0 = 0; k0 < K; k0 += 32) {
        __syncthreads();
#pragma unroll
        for (int i = 0; i < 2; i++) {
            const int grp = w * 2 + i;
            const int row = grp * 16 + brow;
            dma16(A + (size_t)(bm + row) * K + k0 + klog * 8, AsS + grp * 512);
        }
#pragma unroll
        for (int i = 0; i < 2; i++) {
            const int grp = w * 2 + i;
            const int row = grp * 16 + brow;
            dma16(Bt + (size_t)(bn + row) * K + k0 + klog * 8, Bs + grp * 512);
        }
        __syncthreads();

        short8 af[4], bf[4];
#pragma unroll
        for (int i = 0; i < 4; i++) {
            const int row = mb + i * 16 + fr;
            af[i] = *(const short8*)(AsS + row * 32 + (fq ^ ((fr >> 1) & 3)) * 8);
        }
#pragma unroll
        for (int j = 0; j < 4; j++) {
            const int row = nb + j * 16 + fr;
            bf[j] = *(const short8*)(Bs + row * 32 + (fq ^ ((fr >> 1) & 3)) * 8);
        }
#pragma unroll
        for (int i = 0; i < 4; i++)
#pragma unroll
            for (int j = 0; j < 4; j++)
                acc[i * 4 + j] = __builtin_amdgcn_mfma_f32_16x16x32_bf16(
                    af[i], bf[j], acc[i * 4 + j], 0, 0, 0);
    }

    const int nidx = (bm + mb) >> 6;
#pragma unroll
    for (int j = 0; j < 4; j++) {
        const int n = bn + nb + j * 16 + fr;
        const float bv = bias[n];
        float s = 0.f;
#pragma unroll
        for (int i = 0; i < 4; i++) {
            const f32x4 a = acc[i * 4 + j];
#pragma unroll
            for (int r = 0; r < 4; r++) s += fmaxf(a[r] + bv, 0.f);
        }
        s += __shfl_xor(s, 16);
        s += __shfl_xor(s, 32);
        if (fq == 0) cmean[(size_t)nidx * 1024 + n] = s * (1.0f / 64.0f);
    }
}

// ---------- MEGA v8: 64-row tile -> 64KB LDS -> 2 blocks/CU (cross-block overlap) ----------
// r14 lesson closed the in-block path: mega's ~63us is phase-serialization at
// 1 block/CU (r4 TLP, r13 spill-removal, r14 fusion all null/negative).  Only
// untried knob: overlap phases of TWO resident blocks.  64-row tile (4
// graphs/block, 512 blocks): As=64KB -> 2 blocks/CU, 16 waves/CU.  Wave owns
// 64x64 (acc[4][4]=64 regs; ~110 peak <= 128-cap at 4 waves/SIMD -> no spill,
// single pass).  E: w0-3 t1+t3 for graph w; w4-7 S+oms for graph w-4.
// Handoff 4x4096 floats = exactly 64KB overlaid on As.  Fin on w0-3 with
// r8-proven hoisted barriers.  Act stays the standalone r10 kernel.
__global__ __launch_bounds__(512, 2)
void mega_obj_graph(const float* __restrict__ A, const ushort_t* __restrict__ Bt,
                    const float* __restrict__ bias, const ushort_t* __restrict__ act_bf,
                    const ushort_t* __restrict__ W1t, const ushort_t* __restrict__ W3t,
                    const float* __restrict__ b1, const float* __restrict__ b3,
                    const ushort_t* __restrict__ W2b, const float* __restrict__ b2,
                    const ushort_t* __restrict__ W4b, const float* __restrict__ b4,
                    ushort_t* __restrict__ cbuf)
{
    __shared__ __align__(16) ushort_t As[64 * 512];    // 64KB: A-stage -> C-stage -> handoff+fin scratch

    const int t = threadIdx.x;
    const int lane = t & 63, w = t >> 6;               // w in 0..7
    const int bm = blockIdx.x * 64;
    const int fr = lane & 15, fq = lane >> 4;

    // ---- A: stage A fp32 -> bf16 LDS, (row&7) chunk swizzle ----
    const float4* A4 = (const float4*)(A + (size_t)bm * 512);
#pragma unroll
    for (int i = 0; i < 8; i++) {
        const int fl = i * 1024 + t * 2;
        const int row = fl >> 7;                       // = i*8 + w, wave-constant
        const float4 p0 = A4[fl];
        const float4 p1 = A4[fl + 1];
        unsigned rr[4] = { pk2bf(p0.x, p0.y), pk2bf(p0.z, p0.w),
                           pk2bf(p1.x, p1.y), pk2bf(p1.z, p1.w) };
        *(uint4*)&As[row * 512 + ((lane ^ (row & 7)) * 8)] = *(uint4*)rr;
    }

    const int nw = w * 64;
    const ushort_t* Bbase = Bt + (size_t)(nw + fr) * 512 + fq * 8;
    uint4 bA[4], bB[4];
#pragma unroll
    for (int j = 0; j < 4; j++) bA[j] = *(const uint4*)(Bbase + (size_t)j * 16 * 512);

    __syncthreads();

    // ---- B: MFMA main loop, acc[4][4] (rows 0-63 x cols nw..nw+63) ----
    f32x4 acc[4][4];
#pragma unroll
    for (int i = 0; i < 4; i++)
#pragma unroll
        for (int j = 0; j < 4; j++) acc[i][j] = (f32x4){0.f, 0.f, 0.f, 0.f};

    for (int kk = 0; kk < 16; kk += 2) {
        short8 af[4];
#pragma unroll
        for (int i = 0; i < 4; i++)
            af[i] = *(const short8*)&As[(i * 16 + fr) * 512 + (((kk * 4 + fq) ^ (fr & 7)) * 8)];
#pragma unroll
        for (int j = 0; j < 4; j++) {
            bB[j] = *(const uint4*)(Bbase + (size_t)j * 16 * 512 + (kk + 1) * 32);
            const short8 bf = *(const short8*)&bA[j];
#pragma unroll
            for (int i = 0; i < 4; i++)
                acc[i][j] = __builtin_amdgcn_mfma_f32_16x16x32_bf16(af[i], bf, acc[i][j], 0, 0, 0);
        }
#pragma unroll
        for (int i = 0; i < 4; i++)
            af[i] = *(const short8*)&As[(i * 16 + fr) * 512 + ((((kk + 1) * 4 + fq) ^ (fr & 7)) * 8)];
#pragma unroll
        for (int j = 0; j < 4; j++) {
            if (kk + 2 < 16)
                bA[j] = *(const uint4*)(Bbase + (size_t)j * 16 * 512 + (kk + 2) * 32);
            const short8 bf = *(const short8*)&bB[j];
#pragma unroll
            for (int i = 0; i < 4; i++)
                acc[i][j] = __builtin_amdgcn_mfma_f32_16x16x32_bf16(af[i], bf, acc[i][j], 0, 0, 0);
        }
    }

    // ---- C: bias+relu, bf16 C-store into LDS with (m&7) chunk swizzle ----
    __syncthreads();
#pragma unroll
    for (int j = 0; j < 4; j++) {
        const int col0 = nw + j * 16 + fr;
        const float bv = bias[col0];
#pragma unroll
        for (int i = 0; i < 4; i++) {
#pragma unroll
            for (int rr2 = 0; rr2 < 4; rr2++) {
                const int m = i * 16 + fq * 4 + rr2;
                As[m * 512 + ((((col0 >> 3) ^ (m & 7)) << 3) | (col0 & 7))]
                    = f2bf(fmaxf(acc[i][j][rr2] + bv, 0.f));
            }
        }
    }
    __syncthreads();

    // ---- D: inject act rows (m = ra*16+8; m&7==0 -> linear), 4 rows ----
    if (t < 256) {
        const int ra = t >> 6, gg = t & 63;
        const uint4 v = *(const uint4*)(act_bf + (size_t)(blockIdx.x * 4 + ra) * 512 + gg * 8);
        *(uint4*)&As[(ra * 16 + 8) * 512 + gg * 8] = v;
    }
    __syncthreads();

    // ---- E: per-wave pre computations into registers ----
    // w0-3: t1 AND t3 for graph w; w4-7: S = x@x^T + obj col-sums for graph w-4
    f32x4 ea = (f32x4){0.f,0.f,0.f,0.f}, eb = ea, ec = ea, ed = ea;
    float om[8] = {0,0,0,0,0,0,0,0};
    if (w < 4) {
        for (int kk = 0; kk < 16; kk++) {
            const short8 xf = *(const short8*)&As[(w * 16 + fr) * 512 + (((kk * 4 + fq) ^ (fr & 7)) * 8)];
            const short8 w10 = *(const short8*)(W1t + (size_t)fr * 512 + kk * 32 + fq * 8);
            const short8 w11 = *(const short8*)(W1t + (size_t)(16 + fr) * 512 + kk * 32 + fq * 8);
            const short8 w30 = *(const short8*)(W3t + (size_t)fr * 512 + kk * 32 + fq * 8);
            const short8 w31 = *(const short8*)(W3t + (size_t)(16 + fr) * 512 + kk * 32 + fq * 8);
            ea = __builtin_amdgcn_mfma_f32_16x16x32_bf16(xf, w10, ea, 0, 0, 0);
            eb = __builtin_amdgcn_mfma_f32_16x16x32_bf16(xf, w11, eb, 0, 0, 0);
            ec = __builtin_amdgcn_mfma_f32_16x16x32_bf16(xf, w30, ec, 0, 0, 0);
            ed = __builtin_amdgcn_mfma_f32_16x16x32_bf16(xf, w31, ed, 0, 0, 0);
        }
    } else {
        const int g = w - 4;
        for (int kk = 0; kk < 16; kk++) {
            const short8 xf = *(const short8*)&As[(g * 16 + fr) * 512 + (((kk * 4 + fq) ^ (fr & 7)) * 8)];
            ea = __builtin_amdgcn_mfma_f32_16x16x32_bf16(xf, xf, ea, 0, 0, 0);
        }
#pragma unroll
        for (int m = 0; m < 16; m++) {
            const uint4 q = *(const uint4*)&As[(g * 16 + m) * 512 + ((lane ^ (m & 7)) * 8)];
            om[0] += bflo(q.x); om[1] += bfhi(q.x);
            om[2] += bflo(q.y); om[3] += bfhi(q.y);
            om[4] += bflo(q.z); om[5] += bfhi(q.z);
            om[6] += bflo(q.w); om[7] += bfhi(q.w);
        }
    }
    __syncthreads();   // all reads of C-tile done; As free for fp32 handoff

    // ---- handoff: per graph g (0..3), base g*4096 floats:
    //   S[0..255] t1[256..767] t3[768..1279] oms[1280..1791]
    //   x1S[1792..2303] adjS[2304..2575] y2S[2576..3151]
    //   dvS[3152] cAS[3168] nrmS[3184] dv3S[3200] cA3S[3216] zc1S[3232] zc4S[3264]
    float* Hs = (float*)As;
    if (w < 4) {
        float* dst = Hs + (size_t)w * 4096;
#pragma unroll
        for (int i = 0; i < 4; i++) {
            const int m = fq * 4 + i;
            dst[256 + m * 32 + fr]      = ea[i];
            dst[256 + m * 32 + 16 + fr] = eb[i];
            dst[768 + m * 32 + fr]      = ec[i];
            dst[768 + m * 32 + 16 + fr] = ed[i];
        }
    } else {
        const int g = w - 4;
        float* dst = Hs + (size_t)g * 4096;
#pragma unroll
        for (int i = 0; i < 4; i++) {
            const int m = fq * 4 + i;
            dst[m * 16 + fr] = ea[i];
        }
        *(float4*)(dst + 1280 + lane * 8)     = (float4){om[0], om[1], om[2], om[3]};
        *(float4*)(dst + 1280 + lane * 8 + 4) = (float4){om[4], om[5], om[6], om[7]};
    }
    __syncthreads();

    // ---- F: fin chain, waves 0-3 (graph = w); hoisted barriers, 4-7 idle ----
    const int r = fr, q = fq;
    float* Hg   = Hs + (size_t)(w & 3) * 4096;
    float* x1S  = Hg + 1792;
    float* adjS = Hg + 2304;
    float* y2S  = Hg + 2576;
    float* dvS  = Hg + 3152;
    float* cAS  = Hg + 3168;
    float* nrmS = Hg + 3184;
    float* dv3S = Hg + 3200;
    float* cA3S = Hg + 3216;
    float* zc1S = Hg + 3232;
    float* zc4S = Hg + 3264;
    const int c0 = q * 8;

    float e0s = 0.f, e1s = 0.f, e2s = 0.f, e3s = 0.f, dv = 0.f;
    if (w < 4) {
        // P1: softmax over row r of S
        const float4 sv = *(const float4*)(Hg + r * 16 + q * 4);
        float mx = fmaxf(fmaxf(sv.x, sv.y), fmaxf(sv.z, sv.w));
        mx = fmaxf(mx, __shfl_xor(mx, 16));
        mx = fmaxf(mx, __shfl_xor(mx, 32));
        e0s = expf(sv.x - mx); e1s = expf(sv.y - mx);
        e2s = expf(sv.z - mx); e3s = expf(sv.w - mx);
        float rs = e0s + e1s + e2s + e3s;
        rs += __shfl_xor(rs, 16); rs += __shfl_xor(rs, 32);
        dv = rsqrtf(rs);
        if (q == 0) dvS[r] = dv;
    }
    __syncthreads();

    if (w < 4) {
        // P2: adj + fused column sums cA
        const float4 dc = *(const float4*)&dvS[q * 4];
        const float ad0 = e0s * dv * dc.x, ad1 = e1s * dv * dc.y;
        const float ad2 = e2s * dv * dc.z, ad3 = e3s * dv * dc.w;
        adjS[r * 17 + q * 4 + 0] = ad0; adjS[r * 17 + q * 4 + 1] = ad1;
        adjS[r * 17 + q * 4 + 2] = ad2; adjS[r * 17 + q * 4 + 3] = ad3;
        float c0s = ad0, c1s = ad1, c2s = ad2, c3s = ad3;
#pragma unroll
        for (int m = 1; m <= 8; m <<= 1) {
            c0s += __shfl_xor(c0s, m); c1s += __shfl_xor(c1s, m);
            c2s += __shfl_xor(c2s, m); c3s += __shfl_xor(c3s, m);
        }
        if (r == 0) {
            cAS[q * 4 + 0] = c0s; cAS[q * 4 + 1] = c1s;
            cAS[q * 4 + 2] = c2s; cAS[q * 4 + 3] = c3s;
        }
    }
    __syncthreads();

    if (w < 4) {
        // P3: x1 = relu(adj@t1 + b1), y2 = relu(adj@t3 + b3); straight to LDS
        float x1v[8], y2v[8];
        const float4 b1a = *(const float4*)(b1 + c0);
        const float4 b1b = *(const float4*)(b1 + c0 + 4);
        const float4 b3a = *(const float4*)(b3 + c0);
        const float4 b3b = *(const float4*)(b3 + c0 + 4);
        x1v[0]=b1a.x; x1v[1]=b1a.y; x1v[2]=b1a.z; x1v[3]=b1a.w;
        x1v[4]=b1b.x; x1v[5]=b1b.y; x1v[6]=b1b.z; x1v[7]=b1b.w;
        y2v[0]=b3a.x; y2v[1]=b3a.y; y2v[2]=b3a.z; y2v[3]=b3a.w;
        y2v[4]=b3b.x; y2v[5]=b3b.y; y2v[6]=b3b.z; y2v[7]=b3b.w;
#pragma unroll
        for (int j = 0; j < 16; j++) {
            const float a = adjS[r * 17 + j];
            const float4 t1a = *(const float4*)(Hg + 256 + j * 32 + c0);
            const float4 t1b = *(const float4*)(Hg + 256 + j * 32 + c0 + 4);
            const float4 t3a = *(const float4*)(Hg + 768 + j * 32 + c0);
            const float4 t3b = *(const float4*)(Hg + 768 + j * 32 + c0 + 4);
            x1v[0] = fmaf(a, t1a.x, x1v[0]); x1v[1] = fmaf(a, t1a.y, x1v[1]);
            x1v[2] = fmaf(a, t1a.z, x1v[2]); x1v[3] = fmaf(a, t1a.w, x1v[3]);
            x1v[4] = fmaf(a, t1b.x, x1v[4]); x1v[5] = fmaf(a, t1b.y, x1v[5]);
            x1v[6] = fmaf(a, t1b.z, x1v[6]); x1v[7] = fmaf(a, t1b.w, x1v[7]);
            y2v[0] = fmaf(a, t3a.x, y2v[0]); y2v[1] = fmaf(a, t3a.y, y2v[1]);
            y2v[2] = fmaf(a, t3a.z, y2v[2]); y2v[3] = fmaf(a, t3a.w, y2v[3]);
            y2v[4] = fmaf(a, t3b.x, y2v[4]); y2v[5] = fmaf(a, t3b.y, y2v[5]);
            y2v[6] = fmaf(a, t3b.z, y2v[6]); y2v[7] = fmaf(a, t3b.w, y2v[7]);
        }
#pragma unroll
        for (int cc = 0; cc < 8; cc++) {
            x1S[r * 32 + c0 + cc] = fmaxf(x1v[cc], 0.f);
            y2S[r * 36 + c0 + cc] = fmaxf(y2v[cc], 0.f);
        }
    }
    __syncthreads();

    float yy[4] = {0.f, 0.f, 0.f, 0.f};
    if (w < 4) {
        // P4: y22 row-dot + fused row-norm
#pragma unroll
        for (int k4 = 0; k4 < 8; k4++) {
            const float4 yi = *(const float4*)&y2S[r * 36 + k4 * 4];
#pragma unroll
            for (int i = 0; i < 4; i++) {
                const float4 yj = *(const float4*)&y2S[(q * 4 + i) * 36 + k4 * 4];
                yy[i] = fmaf(yi.x, yj.x, yy[i]); yy[i] = fmaf(yi.y, yj.y, yy[i]);
                yy[i] = fmaf(yi.z, yj.z, yy[i]); yy[i] = fmaf(yi.w, yj.w, yy[i]);
            }
        }
        float sq = 0.f;
#pragma unroll
        for (int i = 0; i < 4; i++) sq = fmaf(yy[i], yy[i], sq);
        sq += __shfl_xor(sq, 16); sq += __shfl_xor(sq, 32);
        const float nr = sqrtf(sq);
        if (q == 0) nrmS[r] = nr;
    }
    __syncthreads();

    float a3[4] = {0.f, 0.f, 0.f, 0.f};
    float dv3 = 0.f;
    if (w < 4) {
        // P5: adj3 + fused degree dv3; zc1 via row-reduce of cA * x1 (from LDS)
        const float nr = nrmS[r];
        const float4 ncv = *(const float4*)&nrmS[q * 4];
        a3[0] = 1.0f + yy[0] / (nr * ncv.x);
        a3[1] = 1.0f + yy[1] / (nr * ncv.y);
        a3[2] = 1.0f + yy[2] / (nr * ncv.z);
        a3[3] = 1.0f + yy[3] / (nr * ncv.w);
        float d3 = a3[0] + a3[1] + a3[2] + a3[3];
        d3 += __shfl_xor(d3, 16); d3 += __shfl_xor(d3, 32);
        dv3 = rsqrtf(d3);
        if (q == 0) dv3S[r] = dv3;
        const float cAm = cAS[r];
        const float4 xa = *(const float4*)&x1S[r * 32 + c0];
        const float4 xb = *(const float4*)&x1S[r * 32 + c0 + 4];
        float zp[8] = { cAm * xa.x, cAm * xa.y, cAm * xa.z, cAm * xa.w,
                        cAm * xb.x, cAm * xb.y, cAm * xb.z, cAm * xb.w };
#pragma unroll
        for (int m = 1; m <= 8; m <<= 1)
#pragma unroll
            for (int cc = 0; cc < 8; cc++) zp[cc] += __shfl_xor(zp[cc], m);
        if (r == 0)
#pragma unroll
            for (int cc = 0; cc < 8; cc++) zc1S[c0 + cc] = zp[cc];
    }
    __syncthreads();

    if (w < 4) {
        // P6: cA3
        const float4 d3c = *(const float4*)&dv3S[q * 4];
        float p0 = a3[0] * dv3 * d3c.x, p1 = a3[1] * dv3 * d3c.y;
        float p2 = a3[2] * dv3 * d3c.z, p3 = a3[3] * dv3 * d3c.w;
#pragma unroll
        for (int m = 1; m <= 8; m <<= 1) {
            p0 += __shfl_xor(p0, m); p1 += __shfl_xor(p1, m);
            p2 += __shfl_xor(p2, m); p3 += __shfl_xor(p3, m);
        }
        if (r == 0) {
            cA3S[q * 4 + 0] = p0; cA3S[q * 4 + 1] = p1;
            cA3S[q * 4 + 2] = p2; cA3S[q * 4 + 3] = p3;
        }
    }
    __syncthreads();

    if (w < 4) {
        // P7: zc4 via row-reduce of cA3 * y2 (from LDS)
        const float cA3m = cA3S[r];
        const float4 ya = *(const float4*)&y2S[r * 36 + c0];
        const float4 yb = *(const float4*)&y2S[r * 36 + c0 + 4];
        float zp[8] = { cA3m * ya.x, cA3m * ya.y, cA3m * ya.z, cA3m * ya.w,
                        cA3m * yb.x, cA3m * yb.y, cA3m * yb.z, cA3m * yb.w };
#pragma unroll
        for (int m = 1; m <= 8; m <<= 1)
#pragma unroll
            for (int cc = 0; cc < 8; cc++) zp[cc] += __shfl_xor(zp[cc], m);
        if (r == 0)
#pragma unroll
            for (int cc = 0; cc < 8; cc++) zc4S[c0 + cc] = zp[cc];
    }
    __syncthreads();

    if (w < 4) {
        // P8: GEMV over W2/W4 + combine + store
        float gm[8] = {0,0,0,0,0,0,0,0};
        const ushort_t* w2p = W2b + lane * 8;
        const ushort_t* w4p = W4b + lane * 8;
#pragma unroll 8
        for (int k = 0; k < 32; k++) {
            const float z1 = zc1S[k], z4 = zc4S[k];
            const uint4 u2 = *(const uint4*)(w2p + (size_t)k * 512);
            const uint4 u4 = *(const uint4*)(w4p + (size_t)k * 512);
            gm[0] = fmaf(z1, bflo(u2.x), gm[0]); gm[0] = fmaf(z4, bflo(u4.x), gm[0]);
            gm[1] = fmaf(z1, bfhi(u2.x), gm[1]); gm[1] = fmaf(z4, bfhi(u4.x), gm[1]);
            gm[2] = fmaf(z1, bflo(u2.y), gm[2]); gm[2] = fmaf(z4, bflo(u4.y), gm[2]);
            gm[3] = fmaf(z1, bfhi(u2.y), gm[3]); gm[3] = fmaf(z4, bfhi(u4.y), gm[3]);
            gm[4] = fmaf(z1, bflo(u2.z), gm[4]); gm[4] = fmaf(z4, bflo(u4.z), gm[4]);
            gm[5] = fmaf(z1, bfhi(u2.z), gm[5]); gm[5] = fmaf(z4, bfhi(u4.z), gm[5]);
            gm[6] = fmaf(z1, bflo(u2.w), gm[6]); gm[6] = fmaf(z4, bflo(u4.w), gm[6]);
            gm[7] = fmaf(z1, bfhi(u2.w), gm[7]); gm[7] = fmaf(z4, bfhi(u4.w), gm[7]);
        }
        const float4 oma = *(const float4*)(Hg + 1280 + lane * 8);
        const float4 omb = *(const float4*)(Hg + 1280 + lane * 8 + 4);
        const float omv[8] = {oma.x, oma.y, oma.z, oma.w, omb.x, omb.y, omb.z, omb.w};
        const float4 b2a = *(const float4*)(b2 + lane * 8);
        const float4 b2b = *(const float4*)(b2 + lane * 8 + 4);
        const float4 b4a = *(const float4*)(b4 + lane * 8);
        const float4 b4b = *(const float4*)(b4 + lane * 8 + 4);
        const float bs[8] = { b2a.x + b4a.x, b2a.y + b4a.y, b2a.z + b4a.z, b2a.w + b4a.w,
                              b2b.x + b4b.x, b2b.y + b4b.y, b2b.z + b4b.z, b2b.w + b4b.w };
        ushort_t pk[8];
#pragma unroll
        for (int cc = 0; cc < 8; cc++) {
            const float gmean = 0.5f * bs[cc] + gm[cc] * (1.0f / 32.0f);
            const float feat  = 0.5f * (omv[cc] * 0.0625f + gmean);
            pk[cc] = f2bf(fmaxf(feat, 0.f));
        }
        *(uint4*)(cbuf + (size_t)(blockIdx.x * 4 + w) * 512 + lane * 8) = *(uint4*)pk;
    }
}

// ---------- clf GEMV on transposed W ----------
__global__ __launch_bounds__(256)
void clf_col(const float* __restrict__ cmean, const float* __restrict__ Wt,
             const float* __restrict__ clf_b, float* __restrict__ out)
{
    __shared__ float red[8][33];
    const int j = blockIdx.x;
    const int t = threadIdx.x;
    const int n = t & 31, kp = t >> 5;
    const float* cm = cmean + (size_t)n * 1024 + kp * 128;
    const float* wp = Wt + (size_t)j * 1024 + kp * 128;
    float acc = 0.f;
#pragma unroll
    for (int k = 0; k < 128; k += 4) {
        const float4 c = *(const float4*)(cm + k);
        const float4 wv = *(const float4*)(wp + k);
        acc = fmaf(c.x, wv.x, acc);
        acc = fmaf(c.y, wv.y, acc);
        acc = fmaf(c.z, wv.z, acc);
        acc = fmaf(c.w, wv.w, acc);
    }
    red[kp][n] = acc;
    __syncthreads();
    if (t < 32) {
        float s = red[0][t];
#pragma unroll
        for (int p = 1; p < 8; p++) s += red[p][t];
        out[(size_t)t * 500 + j] = s + clf_b[j];
    }
}

// ---------- launcher ----------
extern "C" void kernel_launch(void* const* d_in, const int* in_sizes, int n_in,
                              void* d_out, int out_size, void* d_ws, size_t ws_size,
                              hipStream_t stream)
{
    const float* object_raw = (const float*)d_in[0];
    const float* action_raw = (const float*)d_in[1];
    const float* W_obj = (const float*)d_in[2];
    const float* b_obj = (const float*)d_in[3];
    const float* W_act = (const float*)d_in[4];
    const float* b_act = (const float*)d_in[5];
    const float* gc1_W = (const float*)d_in[6];
    const float* gc1_b = (const float*)d_in[7];
    const float* gc2_W = (const float*)d_in[8];
    const float* gc2_b = (const float*)d_in[9];
    const float* gc3_W = (const float*)d_in[10];
    const float* gc3_b = (const float*)d_in[11];
    const float* gc4_W = (const float*)d_in[12];
    const float* gc4_b = (const float*)d_in[13];
    const float* fc1_W = (const float*)d_in[14];
    const float* fc1_b = (const float*)d_in[15];
    const float* clf_W = (const float*)d_in[16];
    const float* clf_b = (const float*)d_in[17];

    char* ws = (char*)d_ws;
    const size_t MB = 1024 * 1024;
    ushort_t* act_bf = (ushort_t*)(ws);                        // 2 MB
    ushort_t* cbuf   = (ushort_t*)(ws + 2 * MB);               // 2 MB
    float*    WclfT  = (float*)   (ws + 4 * MB);               // 2 MB
    float*    cmean  = (float*)   (ws + 6 * MB);               // 128 KB
    ushort_t* WobjT  = (ushort_t*)(ws + 7 * MB);               // 512 KB
    ushort_t* WactT  = (ushort_t*)(ws + 7 * MB + 512 * 1024);  // 512 KB
    ushort_t* fc1T   = (ushort_t*)(ws + 8 * MB);               // 1 MB
    ushort_t* W1t    = (ushort_t*)(ws + 9 * MB);
    ushort_t* W3t    = (ushort_t*)(ws + 9 * MB + 32 * 1024);
    ushort_t* W2bf   = (ushort_t*)(ws + 9 * MB + 64 * 1024);
    ushort_t* W4bf   = (ushort_t*)(ws + 9 * MB + 96 * 1024);

    // 1. weight prep
    prep_weights<<<dim3(1584), 256, 0, stream>>>(
        W_obj, WobjT, W_act, WactT, fc1_W, fc1T,
        gc1_W, W1t, gc3_W, W3t, gc2_W, W2bf, gc4_W, W4bf,
        clf_W, WclfT);

    // 2. act GEMM -> act_bf [2048][512]
    gemm_dma<1, float><<<dim3(4, 16), 256, 0, stream>>>(
        action_raw, WactT, b_act, act_bf, 512, 512, 512, 1, 0);

    // 3. MEGA: 64-row tile, 2 blocks/CU, cross-block phase overlap -> cbuf
    mega_obj_graph<<<dim3(512), 512, 0, stream>>>(
        object_raw, WobjT, b_obj, act_bf, W1t, W3t,
        gc1_b, gc3_b, W2bf, gc2_b, W4bf, gc4_b, cbuf);

    // 4. cmean = mean_T(relu(cbuf @ fc1_W + fc1_b))
    gemm_fc1_mean<<<dim3(8, 16), 256, 0, stream>>>(cbuf, fc1T, fc1_b, cmean);

    // 5. out = cmean @ clf_W + clf_b
    clf_col<<<dim3(500), 256, 0, stream>>>(cmean, WclfT, clf_b, (float*)d_out);
}

// Round 16
// 217.065 us; speedup vs baseline: 1.0732x; 1.0732x over previous
//
#include <hip/hip_runtime.h>
#include <hip/hip_bf16.h>

using ushort_t = unsigned short;
using f32x4  = __attribute__((ext_vector_type(4))) float;
using short8 = __attribute__((ext_vector_type(8))) short;

// ---------- bf16 helpers ----------
__device__ __forceinline__ float bflo(unsigned p) {
    union { unsigned u; float f; } x; x.u = p << 16; return x.f;
}
__device__ __forceinline__ float bfhi(unsigned p) {
    union { unsigned u; float f; } x; x.u = p & 0xffff0000u; return x.f;
}
__device__ __forceinline__ ushort_t f2bf(float f) {
    __hip_bfloat16 h = __float2bfloat16(f);   // RTNE
    return *(ushort_t*)&h;
}
__device__ __forceinline__ unsigned pk2bf(float lo, float hi) {
    __hip_bfloat162 h = __float22bfloat162_rn({lo, hi});  // RTNE, packed
    return *(unsigned*)&h;
}

// ---------- combined weight prep ----------
__device__ __forceinline__ void tr_tile(const float* __restrict__ S, ushort_t* __restrict__ D,
                                        int K, int N, int Npad, int bx, int by,
                                        int tx, int ty, float* tile /*32*33*/)
{
    const int k0 = by * 32, n0 = bx * 32;
#pragma unroll
    for (int r = 0; r < 4; r++) {
        const int k = k0 + ty + r * 8, n = n0 + tx;
        tile[(ty + r * 8) * 33 + tx] = (k < K && n < N) ? S[(size_t)k * N + n] : 0.f;
    }
    __syncthreads();
#pragma unroll
    for (int r = 0; r < 4; r++) {
        const int n = n0 + ty + r * 8, k = k0 + tx;
        if (n < Npad && k < K) D[(size_t)n * K + k] = f2bf(tile[tx * 33 + ty + r * 8]);
    }
}

// fp32 -> fp32 transpose (for clf_W)
__device__ __forceinline__ void trf_tile(const float* __restrict__ S, float* __restrict__ D,
                                         int K, int N, int bx, int by,
                                         int tx, int ty, float* tile /*32*33*/)
{
    const int k0 = by * 32, n0 = bx * 32;
#pragma unroll
    for (int r = 0; r < 4; r++) {
        const int k = k0 + ty + r * 8, n = n0 + tx;
        tile[(ty + r * 8) * 33 + tx] = (k < K && n < N) ? S[(size_t)k * N + n] : 0.f;
    }
    __syncthreads();
#pragma unroll
    for (int r = 0; r < 4; r++) {
        const int n = n0 + ty + r * 8, k = k0 + tx;
        if (n < N && k < K) D[(size_t)n * K + k] = tile[tx * 33 + ty + r * 8];
    }
}

__global__ __launch_bounds__(256)
void prep_weights(const float* __restrict__ Wobj, ushort_t* __restrict__ WobjT,
                  const float* __restrict__ Wact, ushort_t* __restrict__ WactT,
                  const float* __restrict__ fc1W, ushort_t* __restrict__ fc1T,
                  const float* __restrict__ gc1W, ushort_t* __restrict__ W1t,
                  const float* __restrict__ gc3W, ushort_t* __restrict__ W3t,
                  const float* __restrict__ gc2W, ushort_t* __restrict__ W2bf,
                  const float* __restrict__ gc4W, ushort_t* __restrict__ W4bf,
                  const float* __restrict__ clfW, float* __restrict__ WclfT)
{
    __shared__ float tile[32 * 33];
    const int b = blockIdx.x;
    const int t = threadIdx.x;
    const int tx = t & 31, ty = t >> 5;

    if (b < 1056) {
        const float* S; ushort_t* D; int K, N, Npad, nt, l;
        if      (b < 256)  { S = Wobj; D = WobjT; K = 512; N = 512;  Npad = 512;  nt = 16; l = b; }
        else if (b < 512)  { S = Wact; D = WactT; K = 512; N = 512;  Npad = 512;  nt = 16; l = b - 256; }
        else if (b < 1024) { S = fc1W; D = fc1T;  K = 512; N = 1024; Npad = 1024; nt = 32; l = b - 512; }
        else if (b < 1040) { S = gc1W; D = W1t;   K = 512; N = 32;   Npad = 32;   nt = 1;  l = b - 1024; }
        else               { S = gc3W; D = W3t;   K = 512; N = 32;   Npad = 32;   nt = 1;  l = b - 1040; }
        tr_tile(S, D, K, N, Npad, l % nt, l / nt, tx, ty, tile);
    } else if (b < 1072) {
        const float* S = (b < 1064) ? gc2W : gc4W;
        ushort_t* D    = (b < 1064) ? W2bf : W4bf;
        const int i = (b < 1064 ? b - 1056 : b - 1064) * 256 + t;
        const float4 x = ((const float4*)S)[2 * i];
        const float4 y = ((const float4*)S)[2 * i + 1];
        unsigned r[4] = { pk2bf(x.x, x.y), pk2bf(x.z, x.w), pk2bf(y.x, y.y), pk2bf(y.z, y.w) };
        ((uint4*)D)[i] = *(uint4*)r;
    } else {
        const int l = b - 1072;
        trf_tile(clfW, WclfT, 1024, 500, l & 15, l >> 4, tx, ty, tile);
    }
}

// ---------- generic MFMA GEMM (proven; used for act) ----------
typedef __attribute__((address_space(1))) void glb_void;
typedef __attribute__((address_space(3))) void lds_void;
__device__ __forceinline__ void dma16(const void* g, void* l) {
    __builtin_amdgcn_global_load_lds((glb_void*)(unsigned long long)(uintptr_t)g,
                                     (lds_void*)(unsigned)(uintptr_t)l, 16, 0, 0);
}

template<int RELU, typename AT>
__global__ __launch_bounds__(256)
void gemm_dma(const AT* __restrict__ A, const ushort_t* __restrict__ Bt,
              const float* __restrict__ bias, ushort_t* __restrict__ C,
              int N, int K, int Nb, int row_mul, int row_add)
{
    __shared__ __align__(16) char     AsRaw[128 * 32 * sizeof(AT)];
    __shared__ __align__(16) ushort_t Bs[128 * 32];
    const int t = threadIdx.x;
    const int lane = t & 63, w = t >> 6;
    const int bm = blockIdx.y * 128, bn = blockIdx.x * 128;
    const int mb = (w & 1) * 64, nb = (w >> 1) * 64;
    const int fr = lane & 15, fq = lane >> 4;

    f32x4 acc[16];
#pragma unroll
    for (int i = 0; i < 16; i++) acc[i] = (f32x4){0.f, 0.f, 0.f, 0.f};

    const int brow = lane >> 2, bk = lane & 3;
    const int klog = bk ^ ((brow >> 1) & 3);
    const int arow = lane >> 3, ag = lane & 7;

    for (int k0 = 0; k0 < K; k0 += 32) {
        __syncthreads();
        if constexpr (sizeof(AT) == 4) {
#pragma unroll
            for (int i = 0; i < 4; i++) {
                const int grp = w * 4 + i;
                const int row = grp * 8 + arow;
                const int gl = ag ^ (row & 7);
                dma16((const float*)A + (size_t)(bm + row) * K + k0 + gl * 4,
                      AsRaw + grp * 1024);
            }
        } else {
#pragma unroll
            for (int i = 0; i < 2; i++) {
                const int grp = w * 2 + i;
                const int row = grp * 16 + brow;
                dma16((const ushort_t*)A + (size_t)(bm + row) * K + k0 + klog * 8,
                      (ushort_t*)AsRaw + grp * 512);
            }
        }
#pragma unroll
        for (int i = 0; i < 2; i++) {
            const int grp = w * 2 + i;
            const int row = grp * 16 + brow;
            dma16(Bt + (size_t)(bn + row) * K + k0 + klog * 8, Bs + grp * 512);
        }
        __syncthreads();

        short8 af[4], bf[4];
        if constexpr (sizeof(AT) == 4) {
#pragma unroll
            for (int i = 0; i < 4; i++) {
                const int row = mb + i * 16 + fr;
                const float* base = (const float*)AsRaw + row * 32;
                const f32x4 p0 = *(const f32x4*)(base + (((2 * fq)     ^ (fr & 7)) * 4));
                const f32x4 p1 = *(const f32x4*)(base + (((2 * fq + 1) ^ (fr & 7)) * 4));
                unsigned rr[4] = { pk2bf(p0.x, p0.y), pk2bf(p0.z, p0.w),
                                   pk2bf(p1.x, p1.y), pk2bf(p1.z, p1.w) };
                af[i] = *(short8*)rr;
            }
        } else {
#pragma unroll
            for (int i = 0; i < 4; i++) {
                const int row = mb + i * 16 + fr;
                af[i] = *(const short8*)((const ushort_t*)AsRaw + row * 32 + (fq ^ ((fr >> 1) & 3)) * 8);
            }
        }
#pragma unroll
        for (int j = 0; j < 4; j++) {
            const int row = nb + j * 16 + fr;
            bf[j] = *(const short8*)(Bs + row * 32 + (fq ^ ((fr >> 1) & 3)) * 8);
        }
#pragma unroll
        for (int i = 0; i < 4; i++)
#pragma unroll
            for (int j = 0; j < 4; j++)
                acc[i * 4 + j] = __builtin_amdgcn_mfma_f32_16x16x32_bf16(
                    af[i], bf[j], acc[i * 4 + j], 0, 0, 0);
    }

#pragma unroll
    for (int j = 0; j < 4; j++) {
        const int n = bn + nb + j * 16 + fr;
        const float bv = (n < Nb) ? bias[n] : 0.f;
#pragma unroll
        for (int i = 0; i < 4; i++) {
            const f32x4 a = acc[i * 4 + j];
#pragma unroll
            for (int r = 0; r < 4; r++) {
                const int m = bm + mb + i * 16 + fq * 4 + r;
                float v = a[r] + bv;
                if (RELU) v = fmaxf(v, 0.f);
                C[((size_t)m * row_mul + row_add) * (size_t)N + n] = f2bf(v);
            }
        }
    }
}

// ---------- fc1 GEMM with fused T-mean epilogue (r3-proven) ----------
__global__ __launch_bounds__(256)
void gemm_fc1_mean(const ushort_t* __restrict__ A, const ushort_t* __restrict__ Bt,
                   const float* __restrict__ bias, float* __restrict__ cmean)
{
    __shared__ __align__(16) ushort_t AsS[128 * 32];
    __shared__ __align__(16) ushort_t Bs[128 * 32];
    const int t = threadIdx.x;
    const int lane = t & 63, w = t >> 6;
    const int bm = blockIdx.y * 128, bn = blockIdx.x * 128;
    const int mb = (w & 1) * 64, nb = (w >> 1) * 64;
    const int fr = lane & 15, fq = lane >> 4;
    const int K = 512;

    f32x4 acc[16];
#pragma unroll
    for (int i = 0; i < 16; i++) acc[i] = (f32x4){0.f, 0.f, 0.f, 0.f};

    const int brow = lane >> 2, bk = lane & 3;
    const int klog = bk ^ ((brow >> 1) & 3);

    for (int k0 = 0; k0 < K; k0 += 32) {
        __syncthreads();
#pragma unroll
        for (int i = 0; i < 2; i++) {
            const int grp = w * 2 + i;
            const int row = grp * 16 + brow;
            dma16(A + (size_t)(bm + row) * K + k0 + klog * 8, AsS + grp * 512);
        }
#pragma unroll
        for (int i = 0; i < 2; i++) {
            const int grp = w * 2 + i;
            const int row = grp * 16 + brow;
            dma16(Bt + (size_t)(bn + row) * K + k0 + klog * 8, Bs + grp * 512);
        }
        __syncthreads();

        short8 af[4], bf[4];
#pragma unroll
        for (int i = 0; i < 4; i++) {
            const int row = mb + i * 16 + fr;
            af[i] = *(const short8*)(AsS + row * 32 + (fq ^ ((fr >> 1) & 3)) * 8);
        }
#pragma unroll
        for (int j = 0; j < 4; j++) {
            const int row = nb + j * 16 + fr;
            bf[j] = *(const short8*)(Bs + row * 32 + (fq ^ ((fr >> 1) & 3)) * 8);
        }
#pragma unroll
        for (int i = 0; i < 4; i++)
#pragma unroll
            for (int j = 0; j < 4; j++)
                acc[i * 4 + j] = __builtin_amdgcn_mfma_f32_16x16x32_bf16(
                    af[i], bf[j], acc[i * 4 + j], 0, 0, 0);
    }

    const int nidx = (bm + mb) >> 6;
#pragma unroll
    for (int j = 0; j < 4; j++) {
        const int n = bn + nb + j * 16 + fr;
        const float bv = bias[n];
        float s = 0.f;
#pragma unroll
        for (int i = 0; i < 4; i++) {
            const f32x4 a = acc[i * 4 + j];
#pragma unroll
            for (int r = 0; r < 4; r++) s += fmaxf(a[r] + bv, 0.f);
        }
        s += __shfl_xor(s, 16);
        s += __shfl_xor(s, 32);
        if (fq == 0) cmean[(size_t)nidx * 1024 + n] = s * (1.0f / 64.0f);
    }
}

// ---------- MEGA (r10 best-measured form: r7 structure, launch_bounds(512,1)) ----------
// Session conclusion: mega's ~63us is a serial phase-chain latency floor.
// In-block TLP (r4), spill elimination (r13), act fusion (r14), and 2-blocks/CU
// tile shrink (r15) all measured null or negative.  This is the fastest form.
__global__ __launch_bounds__(512, 1)
void mega_obj_graph(const float* __restrict__ A, const ushort_t* __restrict__ Bt,
                    const float* __restrict__ bias, const ushort_t* __restrict__ act_bf,
                    const ushort_t* __restrict__ W1t, const ushort_t* __restrict__ W3t,
                    const float* __restrict__ b1, const float* __restrict__ b3,
                    const ushort_t* __restrict__ W2b, const float* __restrict__ b2,
                    const ushort_t* __restrict__ W4b, const float* __restrict__ b4,
                    ushort_t* __restrict__ cbuf)
{
    __shared__ __align__(16) ushort_t As[128 * 512];   // 128KB: A-stage -> C-stage -> fp32 handoff
    __shared__ __align__(16) float fsS[8][992];        // 31KB per-graph fin scratch

    const int t = threadIdx.x;
    const int lane = t & 63, w = t >> 6;               // w in 0..7
    const int bm = blockIdx.x * 128;
    const int fr = lane & 15, fq = lane >> 4;

    // ---- A: stage A fp32 -> bf16 LDS, (row&7) chunk swizzle ----
    const float4* A4 = (const float4*)(A + (size_t)bm * 512);
#pragma unroll
    for (int i = 0; i < 16; i++) {
        const int fl = i * 1024 + t * 2;
        const int row = fl >> 7;
        const float4 p0 = A4[fl];
        const float4 p1 = A4[fl + 1];
        unsigned rr[4] = { pk2bf(p0.x, p0.y), pk2bf(p0.z, p0.w),
                           pk2bf(p1.x, p1.y), pk2bf(p1.z, p1.w) };
        *(uint4*)&As[row * 512 + ((lane ^ (row & 7)) * 8)] = *(uint4*)rr;
    }

    const int nw = w * 64;
    const ushort_t* Bbase = Bt + (size_t)(nw + fr) * 512 + fq * 8;
    uint4 bA[4], bB[4];
#pragma unroll
    for (int j = 0; j < 4; j++) bA[j] = *(const uint4*)(Bbase + (size_t)j * 16 * 512);

    __syncthreads();

    // ---- B: MFMA main loop (r2-proven, B ping-pong) ----
    f32x4 acc[4][8];
#pragma unroll
    for (int j = 0; j < 4; j++)
#pragma unroll
        for (int i = 0; i < 8; i++) acc[j][i] = (f32x4){0.f, 0.f, 0.f, 0.f};

    for (int kk = 0; kk < 16; kk += 2) {
        short8 af[8];
#pragma unroll
        for (int i = 0; i < 8; i++)
            af[i] = *(const short8*)&As[(i * 16 + fr) * 512 + (((kk * 4 + fq) ^ (fr & 7)) * 8)];
#pragma unroll
        for (int j = 0; j < 4; j++) {
            bB[j] = *(const uint4*)(Bbase + (size_t)j * 16 * 512 + (kk + 1) * 32);
            const short8 bf = *(const short8*)&bA[j];
#pragma unroll
            for (int i = 0; i < 8; i++)
                acc[j][i] = __builtin_amdgcn_mfma_f32_16x16x32_bf16(af[i], bf, acc[j][i], 0, 0, 0);
        }
#pragma unroll
        for (int i = 0; i < 8; i++)
            af[i] = *(const short8*)&As[(i * 16 + fr) * 512 + ((((kk + 1) * 4 + fq) ^ (fr & 7)) * 8)];
#pragma unroll
        for (int j = 0; j < 4; j++) {
            if (kk + 2 < 16)
                bA[j] = *(const uint4*)(Bbase + (size_t)j * 16 * 512 + (kk + 2) * 32);
            const short8 bf = *(const short8*)&bB[j];
#pragma unroll
            for (int i = 0; i < 8; i++)
                acc[j][i] = __builtin_amdgcn_mfma_f32_16x16x32_bf16(af[i], bf, acc[j][i], 0, 0, 0);
        }
    }

    // ---- C: bias+relu, bf16 C-store into LDS with (m&7) chunk swizzle ----
    __syncthreads();
#pragma unroll
    for (int j = 0; j < 4; j++) {
        const int col0 = nw + j * 16 + fr;
        const float bv = bias[col0];
#pragma unroll
        for (int i = 0; i < 8; i++) {
#pragma unroll
            for (int rr2 = 0; rr2 < 4; rr2++) {
                const int m = i * 16 + fq * 4 + rr2;
                As[m * 512 + ((((col0 >> 3) ^ (m & 7)) << 3) | (col0 & 7))]
                    = f2bf(fmaxf(acc[j][i][rr2] + bv, 0.f));
            }
        }
    }
    __syncthreads();

    // ---- D: inject act rows (m = ra*16+8; m&7==0 -> linear) ----
    {
        const int ra = t >> 6, gg = t & 63;
        const uint4 v = *(const uint4*)(act_bf + (size_t)(blockIdx.x * 8 + ra) * 512 + gg * 8);
        *(uint4*)&As[(ra * 16 + 8) * 512 + gg * 8] = v;
    }
    __syncthreads();

    // ---- E: per-wave pre computations into registers ----
    // w1: t1 g0-3 | w5: t1 g4-7 | w2: t3 g0-3 | w6: t3 g4-7
    // w0: S+oms g0-1 | w3: g2-3 | w4: g4-5 | w7: g6-7
    f32x4 e0[4], e1[4];
    float om0[8], om1[8];
    const bool isT = (w == 1) || (w == 2) || (w == 5) || (w == 6);
    const int gofs = (w >= 4) ? 4 : 0;
    const int sidx = (w == 0) ? 0 : (w == 3) ? 1 : (w == 4) ? 2 : 3;   // S-wave id
    const int gb = sidx * 2;

    if (isT) {
        const ushort_t* Wt = ((w & 3) == 1) ? W1t : W3t;
#pragma unroll
        for (int g = 0; g < 4; g++) { e0[g] = (f32x4){0.f,0.f,0.f,0.f}; e1[g] = e0[g]; }
        for (int kk = 0; kk < 16; kk++) {
            const short8 wa = *(const short8*)(Wt + (size_t)fr * 512 + kk * 32 + fq * 8);
            const short8 wb = *(const short8*)(Wt + (size_t)(16 + fr) * 512 + kk * 32 + fq * 8);
#pragma unroll
            for (int g = 0; g < 4; g++) {
                const short8 xf = *(const short8*)&As[((gofs + g) * 16 + fr) * 512 + (((kk * 4 + fq) ^ (fr & 7)) * 8)];
                e0[g] = __builtin_amdgcn_mfma_f32_16x16x32_bf16(xf, wa, e0[g], 0, 0, 0);
                e1[g] = __builtin_amdgcn_mfma_f32_16x16x32_bf16(xf, wb, e1[g], 0, 0, 0);
            }
        }
    } else {
        e0[0] = (f32x4){0.f,0.f,0.f,0.f}; e1[0] = e0[0];
        for (int kk = 0; kk < 16; kk++) {
            const short8 xf0 = *(const short8*)&As[(gb * 16 + fr) * 512 + (((kk * 4 + fq) ^ (fr & 7)) * 8)];
            const short8 xf1 = *(const short8*)&As[((gb + 1) * 16 + fr) * 512 + (((kk * 4 + fq) ^ (fr & 7)) * 8)];
            e0[0] = __builtin_amdgcn_mfma_f32_16x16x32_bf16(xf0, xf0, e0[0], 0, 0, 0);
            e1[0] = __builtin_amdgcn_mfma_f32_16x16x32_bf16(xf1, xf1, e1[0], 0, 0, 0);
        }
#pragma unroll
        for (int c = 0; c < 8; c++) { om0[c] = 0.f; om1[c] = 0.f; }
#pragma unroll
        for (int m = 0; m < 16; m++) {
            const uint4 q0 = *(const uint4*)&As[(gb * 16 + m) * 512 + ((lane ^ (m & 7)) * 8)];
            const uint4 q1 = *(const uint4*)&As[((gb + 1) * 16 + m) * 512 + ((lane ^ (m & 7)) * 8)];
            om0[0] += bflo(q0.x); om0[1] += bfhi(q0.x);
            om0[2] += bflo(q0.y); om0[3] += bfhi(q0.y);
            om0[4] += bflo(q0.z); om0[5] += bfhi(q0.z);
            om0[6] += bflo(q0.w); om0[7] += bfhi(q0.w);
            om1[0] += bflo(q1.x); om1[1] += bfhi(q1.x);
            om1[2] += bflo(q1.y); om1[3] += bfhi(q1.y);
            om1[4] += bflo(q1.z); om1[5] += bfhi(q1.z);
            om1[6] += bflo(q1.w); om1[7] += bfhi(q1.w);
        }
    }
    __syncthreads();   // all reads of C-tile done; As free for fp32 handoff

    // ---- handoff: per graph g (0..7): base g*1792: S[256] t1[512] t3[512] oms[512]
    float* Hs = (float*)As;
    if (isT) {
        const int toff = ((w & 3) == 1) ? 256 : 768;
#pragma unroll
        for (int g = 0; g < 4; g++) {
            float* dst = Hs + (gofs + g) * 1792 + toff;
#pragma unroll
            for (int i = 0; i < 4; i++) {
                const int m = fq * 4 + i;
                dst[m * 32 + fr]      = e0[g][i];
                dst[m * 32 + 16 + fr] = e1[g][i];
            }
        }
    } else {
        float* d0 = Hs + gb * 1792;
        float* d1 = Hs + (gb + 1) * 1792;
#pragma unroll
        for (int i = 0; i < 4; i++) {
            const int m = fq * 4 + i;
            d0[m * 16 + fr] = e0[0][i];
            d1[m * 16 + fr] = e1[0][i];
        }
        *(float4*)(d0 + 1280 + lane * 8)     = (float4){om0[0], om0[1], om0[2], om0[3]};
        *(float4*)(d0 + 1280 + lane * 8 + 4) = (float4){om0[4], om0[5], om0[6], om0[7]};
        *(float4*)(d1 + 1280 + lane * 8)     = (float4){om1[0], om1[1], om1[2], om1[3]};
        *(float4*)(d1 + 1280 + lane * 8 + 4) = (float4){om1[4], om1[5], om1[6], om1[7]};
    }
    __syncthreads();

    // ---- F: fin chain, one wave per graph (graph = w), r5-proven math ----
    {
        const int r = fr, q = fq;
        const float* Hg = Hs + w * 1792;                 // S at 0, t1 at 256, t3 at 768, oms at 1280
        float* fw   = fsS[w];
        float* adjS = fw;            // 16*17 = 272
        float* y2S  = fw + 272;      // 16*36 = 576
        float* dvS  = fw + 848;
        float* cAS  = fw + 864;
        float* nrmS = fw + 880;
        float* dv3S = fw + 896;
        float* cA3S = fw + 912;
        float* zc1S = fw + 928;      // 32
        float* zc4S = fw + 960;      // 32

        // P1: softmax over row r of S
        const float4 sv = *(const float4*)(Hg + r * 16 + q * 4);
        float mx = fmaxf(fmaxf(sv.x, sv.y), fmaxf(sv.z, sv.w));
        mx = fmaxf(mx, __shfl_xor(mx, 16));
        mx = fmaxf(mx, __shfl_xor(mx, 32));
        const float e0s = expf(sv.x - mx), e1s = expf(sv.y - mx);
        const float e2s = expf(sv.z - mx), e3s = expf(sv.w - mx);
        float rs = e0s + e1s + e2s + e3s;
        rs += __shfl_xor(rs, 16); rs += __shfl_xor(rs, 32);
        const float dv = rsqrtf(rs);
        if (q == 0) dvS[r] = dv;
        __syncthreads();

        // P2: adj + fused column sums cA
        float ad0, ad1, ad2, ad3;
        {
            const float4 dc = *(const float4*)&dvS[q * 4];
            ad0 = e0s * dv * dc.x; ad1 = e1s * dv * dc.y;
            ad2 = e2s * dv * dc.z; ad3 = e3s * dv * dc.w;
        }
        adjS[r * 17 + q * 4 + 0] = ad0; adjS[r * 17 + q * 4 + 1] = ad1;
        adjS[r * 17 + q * 4 + 2] = ad2; adjS[r * 17 + q * 4 + 3] = ad3;
        {
            float c0s = ad0, c1s = ad1, c2s = ad2, c3s = ad3;
#pragma unroll
            for (int m = 1; m <= 8; m <<= 1) {
                c0s += __shfl_xor(c0s, m); c1s += __shfl_xor(c1s, m);
                c2s += __shfl_xor(c2s, m); c3s += __shfl_xor(c3s, m);
            }
            if (r == 0) {
                cAS[q * 4 + 0] = c0s; cAS[q * 4 + 1] = c1s;
                cAS[q * 4 + 2] = c2s; cAS[q * 4 + 3] = c3s;
            }
        }
        __syncthreads();

        // P3: x1 = relu(adj@t1 + b1), y2 = relu(adj@t3 + b3); row r, cols q*8..+7
        const int c0 = q * 8;
        float x1v[8], y2v[8];
        {
            const float4 b1a = *(const float4*)(b1 + c0);
            const float4 b1b = *(const float4*)(b1 + c0 + 4);
            const float4 b3a = *(const float4*)(b3 + c0);
            const float4 b3b = *(const float4*)(b3 + c0 + 4);
            x1v[0]=b1a.x; x1v[1]=b1a.y; x1v[2]=b1a.z; x1v[3]=b1a.w;
            x1v[4]=b1b.x; x1v[5]=b1b.y; x1v[6]=b1b.z; x1v[7]=b1b.w;
            y2v[0]=b3a.x; y2v[1]=b3a.y; y2v[2]=b3a.z; y2v[3]=b3a.w;
            y2v[4]=b3b.x; y2v[5]=b3b.y; y2v[6]=b3b.z; y2v[7]=b3b.w;
        }
#pragma unroll
        for (int j = 0; j < 16; j++) {
            const float a = adjS[r * 17 + j];
            const float4 t1a = *(const float4*)(Hg + 256 + j * 32 + c0);
            const float4 t1b = *(const float4*)(Hg + 256 + j * 32 + c0 + 4);
            const float4 t3a = *(const float4*)(Hg + 768 + j * 32 + c0);
            const float4 t3b = *(const float4*)(Hg + 768 + j * 32 + c0 + 4);
            x1v[0] = fmaf(a, t1a.x, x1v[0]); x1v[1] = fmaf(a, t1a.y, x1v[1]);
            x1v[2] = fmaf(a, t1a.z, x1v[2]); x1v[3] = fmaf(a, t1a.w, x1v[3]);
            x1v[4] = fmaf(a, t1b.x, x1v[4]); x1v[5] = fmaf(a, t1b.y, x1v[5]);
            x1v[6] = fmaf(a, t1b.z, x1v[6]); x1v[7] = fmaf(a, t1b.w, x1v[7]);
            y2v[0] = fmaf(a, t3a.x, y2v[0]); y2v[1] = fmaf(a, t3a.y, y2v[1]);
            y2v[2] = fmaf(a, t3a.z, y2v[2]); y2v[3] = fmaf(a, t3a.w, y2v[3]);
            y2v[4] = fmaf(a, t3b.x, y2v[4]); y2v[5] = fmaf(a, t3b.y, y2v[5]);
            y2v[6] = fmaf(a, t3b.z, y2v[6]); y2v[7] = fmaf(a, t3b.w, y2v[7]);
        }
#pragma unroll
        for (int cc = 0; cc < 8; cc++) {
            x1v[cc] = fmaxf(x1v[cc], 0.f);
            y2v[cc] = fmaxf(y2v[cc], 0.f);
            y2S[r * 36 + c0 + cc] = y2v[cc];
        }
        __syncthreads();

        // P4: y22 row-dot + fused row-norm
        float yy[4] = {0.f, 0.f, 0.f, 0.f};
#pragma unroll
        for (int k4 = 0; k4 < 8; k4++) {
            const float4 yi = *(const float4*)&y2S[r * 36 + k4 * 4];
#pragma unroll
            for (int i = 0; i < 4; i++) {
                const float4 yj = *(const float4*)&y2S[(q * 4 + i) * 36 + k4 * 4];
                yy[i] = fmaf(yi.x, yj.x, yy[i]); yy[i] = fmaf(yi.y, yj.y, yy[i]);
                yy[i] = fmaf(yi.z, yj.z, yy[i]); yy[i] = fmaf(yi.w, yj.w, yy[i]);
            }
        }
        {
            float sq = 0.f;
#pragma unroll
            for (int i = 0; i < 4; i++) sq = fmaf(yy[i], yy[i], sq);
            sq += __shfl_xor(sq, 16); sq += __shfl_xor(sq, 32);
            const float nr = sqrtf(sq);
            if (q == 0) nrmS[r] = nr;
        }
        __syncthreads();

        // P5: adj3 + fused degree dv3; zc1 via row-reduce of cA*x1
        float a3[4];
        float dv3;
        {
            const float nr = nrmS[r];
            const float4 ncv = *(const float4*)&nrmS[q * 4];
            a3[0] = 1.0f + yy[0] / (nr * ncv.x);
            a3[1] = 1.0f + yy[1] / (nr * ncv.y);
            a3[2] = 1.0f + yy[2] / (nr * ncv.z);
            a3[3] = 1.0f + yy[3] / (nr * ncv.w);
            float d3 = a3[0] + a3[1] + a3[2] + a3[3];
            d3 += __shfl_xor(d3, 16); d3 += __shfl_xor(d3, 32);
            dv3 = rsqrtf(d3);
            if (q == 0) dv3S[r] = dv3;
        }
        {
            const float cAm = cAS[r];
            float zp[8];
#pragma unroll
            for (int cc = 0; cc < 8; cc++) zp[cc] = cAm * x1v[cc];
#pragma unroll
            for (int m = 1; m <= 8; m <<= 1)
#pragma unroll
                for (int cc = 0; cc < 8; cc++) zp[cc] += __shfl_xor(zp[cc], m);
            if (r == 0)
#pragma unroll
                for (int cc = 0; cc < 8; cc++) zc1S[c0 + cc] = zp[cc];
        }
        __syncthreads();

        // P6: cA3
        {
            const float4 d3c = *(const float4*)&dv3S[q * 4];
            float p0 = a3[0] * dv3 * d3c.x, p1 = a3[1] * dv3 * d3c.y;
            float p2 = a3[2] * dv3 * d3c.z, p3 = a3[3] * dv3 * d3c.w;
#pragma unroll
            for (int m = 1; m <= 8; m <<= 1) {
                p0 += __shfl_xor(p0, m); p1 += __shfl_xor(p1, m);
                p2 += __shfl_xor(p2, m); p3 += __shfl_xor(p3, m);
            }
            if (r == 0) {
                cA3S[q * 4 + 0] = p0; cA3S[q * 4 + 1] = p1;
                cA3S[q * 4 + 2] = p2; cA3S[q * 4 + 3] = p3;
            }
        }
        __syncthreads();

        // P7: zc4
        {
            const float cA3m = cA3S[r];
            float zp[8];
#pragma unroll
            for (int cc = 0; cc < 8; cc++) zp[cc] = cA3m * y2v[cc];
#pragma unroll
            for (int m = 1; m <= 8; m <<= 1)
#pragma unroll
                for (int cc = 0; cc < 8; cc++) zp[cc] += __shfl_xor(zp[cc], m);
            if (r == 0)
#pragma unroll
                for (int cc = 0; cc < 8; cc++) zc4S[c0 + cc] = zp[cc];
        }
        __syncthreads();

        // P8: GEMV over W2/W4 + combine + store
        {
            float gm[8] = {0,0,0,0,0,0,0,0};
            const ushort_t* w2p = W2b + lane * 8;
            const ushort_t* w4p = W4b + lane * 8;
#pragma unroll 8
            for (int k = 0; k < 32; k++) {
                const float z1 = zc1S[k], z4 = zc4S[k];
                const uint4 u2 = *(const uint4*)(w2p + (size_t)k * 512);
                const uint4 u4 = *(const uint4*)(w4p + (size_t)k * 512);
                gm[0] = fmaf(z1, bflo(u2.x), gm[0]); gm[0] = fmaf(z4, bflo(u4.x), gm[0]);
                gm[1] = fmaf(z1, bfhi(u2.x), gm[1]); gm[1] = fmaf(z4, bfhi(u4.x), gm[1]);
                gm[2] = fmaf(z1, bflo(u2.y), gm[2]); gm[2] = fmaf(z4, bflo(u4.y), gm[2]);
                gm[3] = fmaf(z1, bfhi(u2.y), gm[3]); gm[3] = fmaf(z4, bfhi(u4.y), gm[3]);
                gm[4] = fmaf(z1, bflo(u2.z), gm[4]); gm[4] = fmaf(z4, bflo(u4.z), gm[4]);
                gm[5] = fmaf(z1, bfhi(u2.z), gm[5]); gm[5] = fmaf(z4, bfhi(u4.z), gm[5]);
                gm[6] = fmaf(z1, bflo(u2.w), gm[6]); gm[6] = fmaf(z4, bflo(u4.w), gm[6]);
                gm[7] = fmaf(z1, bfhi(u2.w), gm[7]); gm[7] = fmaf(z4, bfhi(u4.w), gm[7]);
            }
            const float4 oma = *(const float4*)(Hg + 1280 + lane * 8);
            const float4 omb = *(const float4*)(Hg + 1280 + lane * 8 + 4);
            const float omv[8] = {oma.x, oma.y, oma.z, oma.w, omb.x, omb.y, omb.z, omb.w};
            const float4 b2a = *(const float4*)(b2 + lane * 8);
            const float4 b2b = *(const float4*)(b2 + lane * 8 + 4);
            const float4 b4a = *(const float4*)(b4 + lane * 8);
            const float4 b4b = *(const float4*)(b4 + lane * 8 + 4);
            const float bs[8] = { b2a.x + b4a.x, b2a.y + b4a.y, b2a.z + b4a.z, b2a.w + b4a.w,
                                  b2b.x + b4b.x, b2b.y + b4b.y, b2b.z + b4b.z, b2b.w + b4b.w };
            ushort_t pk[8];
#pragma unroll
            for (int cc = 0; cc < 8; cc++) {
                const float gmean = 0.5f * bs[cc] + gm[cc] * (1.0f / 32.0f);
                const float feat  = 0.5f * (omv[cc] * 0.0625f + gmean);
                pk[cc] = f2bf(fmaxf(feat, 0.f));
            }
            *(uint4*)(cbuf + (size_t)(blockIdx.x * 8 + w) * 512 + lane * 8) = *(uint4*)pk;
        }
    }
}

// ---------- clf GEMV on transposed W ----------
__global__ __launch_bounds__(256)
void clf_col(const float* __restrict__ cmean, const float* __restrict__ Wt,
             const float* __restrict__ clf_b, float* __restrict__ out)
{
    __shared__ float red[8][33];
    const int j = blockIdx.x;
    const int t = threadIdx.x;
    const int n = t & 31, kp = t >> 5;
    const float* cm = cmean + (size_t)n * 1024 + kp * 128;
    const float* wp = Wt + (size_t)j * 1024 + kp * 128;
    float acc = 0.f;
#pragma unroll
    for (int k = 0; k < 128; k += 4) {
        const float4 c = *(const float4*)(cm + k);
        const float4 wv = *(const float4*)(wp + k);
        acc = fmaf(c.x, wv.x, acc);
        acc = fmaf(c.y, wv.y, acc);
        acc = fmaf(c.z, wv.z, acc);
        acc = fmaf(c.w, wv.w, acc);
    }
    red[kp][n] = acc;
    __syncthreads();
    if (t < 32) {
        float s = red[0][t];
#pragma unroll
        for (int p = 1; p < 8; p++) s += red[p][t];
        out[(size_t)t * 500 + j] = s + clf_b[j];
    }
}

// ---------- launcher ----------
extern "C" void kernel_launch(void* const* d_in, const int* in_sizes, int n_in,
                              void* d_out, int out_size, void* d_ws, size_t ws_size,
                              hipStream_t stream)
{
    const float* object_raw = (const float*)d_in[0];
    const float* action_raw = (const float*)d_in[1];
    const float* W_obj = (const float*)d_in[2];
    const float* b_obj = (const float*)d_in[3];
    const float* W_act = (const float*)d_in[4];
    const float* b_act = (const float*)d_in[5];
    const float* gc1_W = (const float*)d_in[6];
    const float* gc1_b = (const float*)d_in[7];
    const float* gc2_W = (const float*)d_in[8];
    const float* gc2_b = (const float*)d_in[9];
    const float* gc3_W = (const float*)d_in[10];
    const float* gc3_b = (const float*)d_in[11];
    const float* gc4_W = (const float*)d_in[12];
    const float* gc4_b = (const float*)d_in[13];
    const float* fc1_W = (const float*)d_in[14];
    const float* fc1_b = (const float*)d_in[15];
    const float* clf_W = (const float*)d_in[16];
    const float* clf_b = (const float*)d_in[17];

    char* ws = (char*)d_ws;
    const size_t MB = 1024 * 1024;
    ushort_t* act_bf = (ushort_t*)(ws);                        // 2 MB
    ushort_t* cbuf   = (ushort_t*)(ws + 2 * MB);               // 2 MB
    float*    WclfT  = (float*)   (ws + 4 * MB);               // 2 MB
    float*    cmean  = (float*)   (ws + 6 * MB);               // 128 KB
    ushort_t* WobjT  = (ushort_t*)(ws + 7 * MB);               // 512 KB
    ushort_t* WactT  = (ushort_t*)(ws + 7 * MB + 512 * 1024);  // 512 KB
    ushort_t* fc1T   = (ushort_t*)(ws + 8 * MB);               // 1 MB
    ushort_t* W1t    = (ushort_t*)(ws + 9 * MB);
    ushort_t* W3t    = (ushort_t*)(ws + 9 * MB + 32 * 1024);
    ushort_t* W2bf   = (ushort_t*)(ws + 9 * MB + 64 * 1024);
    ushort_t* W4bf   = (ushort_t*)(ws + 9 * MB + 96 * 1024);

    // 1. weight prep
    prep_weights<<<dim3(1584), 256, 0, stream>>>(
        W_obj, WobjT, W_act, WactT, fc1_W, fc1T,
        gc1_W, W1t, gc3_W, W3t, gc2_W, W2bf, gc4_W, W4bf,
        clf_W, WclfT);

    // 2. act GEMM -> act_bf [2048][512]
    gemm_dma<1, float><<<dim3(4, 16), 256, 0, stream>>>(
        action_raw, WactT, b_act, act_bf, 512, 512, 512, 1, 0);

    // 3. MEGA: obj GEMM + graph pre + graph fin -> cbuf
    mega_obj_graph<<<dim3(256), 512, 0, stream>>>(
        object_raw, WobjT, b_obj, act_bf, W1t, W3t,
        gc1_b, gc3_b, W2bf, gc2_b, W4bf, gc4_b, cbuf);

    // 4. cmean = mean_T(relu(cbuf @ fc1_W + fc1_b))
    gemm_fc1_mean<<<dim3(8, 16), 256, 0, stream>>>(cbuf, fc1T, fc1_b, cmean);

    // 5. out = cmean @ clf_W + clf_b
    clf_col<<<dim3(500), 256, 0, stream>>>(cmean, WclfT, clf_b, (float*)d_out);
}